// Round 11
// baseline (205.618 us; speedup 1.0000x reference)
//
#include <hip/hip_runtime.h>
#include <cstdint>

#define Bn 64
#define Ln 512
#define Hn 768
#define Tn 16
#define Cn 8      // chunks over L
#define Sn 64     // chunk length
#define Kn 4      // K-split for GEMM
#define Kc 192    // K-slice per GEMM block (768/4)
#define Mrows (Bn*Ln)   // 32768
#define LOG16 2.7725887222397812f

// ---------------- K_A: partial GEMM, split-K, 2-rows x 4-t per thread ----------------
// r10 arithmetic: W broadcast reads were the binding pipe (64+8 ds_read_b128/chunk
// = 864 cyc vs 512 VALU cyc).  2 rows x 4 t's per thread (same 8 acc regs) cuts
// LDS to 32+16 reads = 576 cyc — balanced with VALU.  Per-output fmaf chain
// (cc asc, j asc, xyzw) unchanged -> partial BIT-IDENTICAL.  Outputs stage via
// LDS (stride 17) and dump as one contiguous 8KB block -> full-line writes (the
// 16B-granular direct store would re-trigger r1's RMW).
__global__ __launch_bounds__(256, 4) void k_gemm_part(
    const float* __restrict__ hs, const float* __restrict__ W,
    float* __restrict__ partial, float* __restrict__ lossws) {
  int bx = blockIdx.x;
  int tid = threadIdx.x;
  if (bx == 0 && tid == 0) {               // zero loss accumulator + ticket each iter
    lossws[0] = 0.f;
    ((int*)lossws)[1] = 0;
  }
  int rt = bx >> 2, s = bx & 3;
  int r0 = rt * 128, kb = s * Kc;
  int lane = tid & 63, wid = tid >> 6;
  int row_a = lane;                           // this thread: rows lane, lane+64
  int t0 = wid * 4;                           // wave-uniform t-quarter
  __shared__ float alds[128 * 36];            // 18,432 B (stride 36: 0 conflicts measured)
  __shared__ float wlds[16 * 192];            // 12,288 B: W slice, broadcast-read
  float accA0 = 0.f, accA1 = 0.f, accA2 = 0.f, accA3 = 0.f;   // row_a,  t0..t0+3
  float accB0 = 0.f, accB1 = 0.f, accB2 = 0.f, accB3 = 0.f;   // row_a+64
  // stage W slice once (768 float4, 3/thread, 16B runs per t-row)
  for (int idx = tid; idx < 768; idx += 256) {
    int t = idx / 48, jj = idx - t * 48;
    *(float4*)&wlds[t * 192 + jj * 4] = *(const float4*)(W + (size_t)t * Hn + kb + jj * 4);
  }
  // staging slots (lineage map, named scalars — r10 form, rule #20)
  int rr = tid >> 3, jj4 = (tid & 7) * 4;
  const float* s0 = hs + (size_t)(r0 + rr)      * Hn + kb + jj4;
  const float* s1 = hs + (size_t)(r0 + rr + 32) * Hn + kb + jj4;
  const float* s2 = hs + (size_t)(r0 + rr + 64) * Hn + kb + jj4;
  const float* s3 = hs + (size_t)(r0 + rr + 96) * Hn + kb + jj4;
  float* d0 = &alds[(rr)      * 36 + jj4];
  float* d1 = &alds[(rr + 32) * 36 + jj4];
  float* d2 = &alds[(rr + 64) * 36 + jj4];
  float* d3 = &alds[(rr + 96) * 36 + jj4];
  float4 pv0 = *(const float4*)(s0);          // chunk 0
  float4 pv1 = *(const float4*)(s1);
  float4 pv2 = *(const float4*)(s2);
  float4 pv3 = *(const float4*)(s3);
#pragma unroll 1
  for (int cc = 0; cc < 6; ++cc) {            // 6 sub-chunks of 32 K-floats
    *(float4*)d0 = pv0;                       // commit prefetched regs to LDS
    *(float4*)d1 = pv1;
    *(float4*)d2 = pv2;
    *(float4*)d3 = pv3;
    __syncthreads();                          // covers W staging at cc=0 too
    if (cc < 5) {                             // issue next chunk's loads under the FMAs
      int off = (cc + 1) * 32;
      pv0 = *(const float4*)(s0 + off);
      pv1 = *(const float4*)(s1 + off);
      pv2 = *(const float4*)(s2 + off);
      pv3 = *(const float4*)(s3 + off);
    }
#pragma unroll
    for (int j = 0; j < 8; ++j) {             // EXACT lineage nest per output: j asc, xyzw
      float4 aa = *(const float4*)&alds[row_a * 36 + j * 4];
      float4 ab = *(const float4*)&alds[(row_a + 64) * 36 + j * 4];
      float4 w0 = *(const float4*)&wlds[(t0 + 0) * 192 + cc * 32 + j * 4];  // broadcast
      float4 w1 = *(const float4*)&wlds[(t0 + 1) * 192 + cc * 32 + j * 4];
      float4 w2 = *(const float4*)&wlds[(t0 + 2) * 192 + cc * 32 + j * 4];
      float4 w3 = *(const float4*)&wlds[(t0 + 3) * 192 + cc * 32 + j * 4];
      accA0 = fmaf(aa.x, w0.x, fmaf(aa.y, w0.y, fmaf(aa.z, w0.z, fmaf(aa.w, w0.w, accA0))));
      accA1 = fmaf(aa.x, w1.x, fmaf(aa.y, w1.y, fmaf(aa.z, w1.z, fmaf(aa.w, w1.w, accA1))));
      accA2 = fmaf(aa.x, w2.x, fmaf(aa.y, w2.y, fmaf(aa.z, w2.z, fmaf(aa.w, w2.w, accA2))));
      accA3 = fmaf(aa.x, w3.x, fmaf(aa.y, w3.y, fmaf(aa.z, w3.z, fmaf(aa.w, w3.w, accA3))));
      accB0 = fmaf(ab.x, w0.x, fmaf(ab.y, w0.y, fmaf(ab.z, w0.z, fmaf(ab.w, w0.w, accB0))));
      accB1 = fmaf(ab.x, w1.x, fmaf(ab.y, w1.y, fmaf(ab.z, w1.z, fmaf(ab.w, w1.w, accB1))));
      accB2 = fmaf(ab.x, w2.x, fmaf(ab.y, w2.y, fmaf(ab.z, w2.z, fmaf(ab.w, w2.w, accB2))));
      accB3 = fmaf(ab.x, w3.x, fmaf(ab.y, w3.y, fmaf(ab.z, w3.z, fmaf(ab.w, w3.w, accB3))));
    }
    __syncthreads();
  }
  // output staging: alds free after the last barrier.  Stride 17 (2-way, free).
  float* outs = alds;
  outs[row_a * 17 + t0 + 0] = accA0;
  outs[row_a * 17 + t0 + 1] = accA1;
  outs[row_a * 17 + t0 + 2] = accA2;
  outs[row_a * 17 + t0 + 3] = accA3;
  outs[(row_a + 64) * 17 + t0 + 0] = accB0;
  outs[(row_a + 64) * 17 + t0 + 1] = accB1;
  outs[(row_a + 64) * 17 + t0 + 2] = accB2;
  outs[(row_a + 64) * 17 + t0 + 3] = accB3;
  __syncthreads();
  // contiguous 8KB dump: 512 float4, 2 per thread -> full-line HBM writes
  float* base = partial + ((size_t)s * Mrows + r0) * Tn;
  int v1 = tid, v2 = tid + 256;
  float4 o1 = make_float4(outs[(v1 >> 2) * 17 + (v1 & 3) * 4 + 0],
                          outs[(v1 >> 2) * 17 + (v1 & 3) * 4 + 1],
                          outs[(v1 >> 2) * 17 + (v1 & 3) * 4 + 2],
                          outs[(v1 >> 2) * 17 + (v1 & 3) * 4 + 3]);
  float4 o2 = make_float4(outs[(v2 >> 2) * 17 + (v2 & 3) * 4 + 0],
                          outs[(v2 >> 2) * 17 + (v2 & 3) * 4 + 1],
                          outs[(v2 >> 2) * 17 + (v2 & 3) * 4 + 2],
                          outs[(v2 >> 2) * 17 + (v2 & 3) * 4 + 3]);
  *(float4*)(base + v1 * 4) = o1;
  *(float4*)(base + v2 * 4) = o2;
}

// ---------------- K_B: reduce+em, then ONE scan per block; TREE inner steps ---------
// blocks 0..511: reduce + denom scan (+em write); 512..1023: reduce + Viterbi.
// This round: depth-4/5 trees with NAMED SCALARS (r2 proved tree semantics pass;
// r2's regression was its pr[16]/bv[16] arrays -> scratch, rule #20).  Viterbi
// tree == sequential first-max exactly (left-preference strict >, right indices
// larger) -> hist/tags unchanged.  Denom tree shifts qmat by ulps (loss only).
// exp(em) precomputed in phase 0 -> off the sched_barrier-pinned chain.
__global__ __launch_bounds__(256) void k_em_scan(
    const float* __restrict__ partial, const float* __restrict__ bias,
    const int* __restrict__ mask, const float* __restrict__ trans,
    float* __restrict__ em, float* __restrict__ qmat,
    float* __restrict__ qv, uint8_t* __restrict__ hist) {
  int half = blockIdx.x >> 9, bc = blockIdx.x & 511;
  int b = bc >> 3, c = bc & 7;
  int tid = threadIdx.x, i = tid >> 4, tp = tid & 15;
  int l0 = c * Sn;
  __shared__ float ems[Sn * Tn];
  __shared__ float cse[Sn * Tn];         // exp(em) (denom half uses it)
  __shared__ int msk[Sn];
  __shared__ float pbuf[256];            // per-group broadcast row (16 floats/group)
  __shared__ uint8_t hl[Tn * Sn * Tn];   // 16 KB (used by half 1 only)
  // phase 0: reduce partial -> em (bit-identical order: bias + s0..s3)
#pragma unroll
  for (int g = 0; g < 4; ++g) {
    int rl = (tid >> 4) + g * 16, t = tid & 15;
    int grow = bc * Sn + rl;
    float sum = bias[t];
#pragma unroll
    for (int s = 0; s < Kn; ++s) sum += partial[((size_t)s * Mrows + grow) * Tn + t];
    float mx = sum;
    mx = fmaxf(mx, __shfl_xor(mx, 1));
    mx = fmaxf(mx, __shfl_xor(mx, 2));
    mx = fmaxf(mx, __shfl_xor(mx, 4));
    mx = fmaxf(mx, __shfl_xor(mx, 8));
    float ev = sum - (mx + LOG16);
    ems[rl * Tn + t] = ev;
    cse[rl * Tn + t] = __expf(ev);
    if (half == 0) em[(size_t)grow * Tn + t] = ev;
  }
  if (tid < Sn) msk[tid] = mask[b * Ln + l0 + tid];
  __syncthreads();
  int lstart = (c == 0) ? 1 : l0;
  int gb = i << 4;                       // group base in pbuf (64B aligned)
  if (half == 0) {
    // denominator scan (linear space, renorm every 16); tree dot (named scalars)
    float etr[Tn];
#pragma unroll
    for (int t = 0; t < Tn; ++t) etr[t] = __expf(trans[t * Tn + tp]);
    float p = (tp == i) ? 1.f : 0.f;
    float logs = 0.f;
    for (int l = lstart; l < l0 + Sn; ++l) {
      pbuf[tid] = p;
      __builtin_amdgcn_sched_barrier(0);
      float4 q0 = *(const float4*)&pbuf[gb + 0];
      float4 q1 = *(const float4*)&pbuf[gb + 4];
      float4 q2 = *(const float4*)&pbuf[gb + 8];
      float4 q3 = *(const float4*)&pbuf[gb + 12];
      float a0  = q0.x * etr[0],  a1  = q0.y * etr[1],  a2  = q0.z * etr[2],  a3  = q0.w * etr[3];
      float a4  = q1.x * etr[4],  a5  = q1.y * etr[5],  a6  = q1.z * etr[6],  a7  = q1.w * etr[7];
      float a8  = q2.x * etr[8],  a9  = q2.y * etr[9],  a10 = q2.z * etr[10], a11 = q2.w * etr[11];
      float a12 = q3.x * etr[12], a13 = q3.y * etr[13], a14 = q3.z * etr[14], a15 = q3.w * etr[15];
      float dot = (((a0 + a1) + (a2 + a3)) + ((a4 + a5) + (a6 + a7)))
                + (((a8 + a9) + (a10 + a11)) + ((a12 + a13) + (a14 + a15)));
      float pn = dot * cse[(l - l0) * Tn + tp];
      p = msk[l - l0] ? pn : p;
      if ((l & 15) == 15) {
        float m = p;
        m = fmaxf(m, __shfl_xor(m, 1));
        m = fmaxf(m, __shfl_xor(m, 2));
        m = fmaxf(m, __shfl_xor(m, 4));
        m = fmaxf(m, __shfl_xor(m, 8));
        p /= m;
        logs += __logf(m);
      }
    }
    qmat[(((size_t)b * Cn + c) * Tn + i) * Tn + tp] = __logf(p) + logs;
  } else {
    // Viterbi scan; tree (max,argmax), named scalars — EXACT first-max
    float tcol[Tn];
#pragma unroll
    for (int t = 0; t < Tn; ++t) tcol[t] = trans[t * Tn + tp];
    float v = (tp == i) ? 0.f : -1e30f;
    for (int l = lstart; l < l0 + Sn; ++l) {
      pbuf[tid] = v;
      __builtin_amdgcn_sched_barrier(0);
      float4 q0 = *(const float4*)&pbuf[gb + 0];
      float4 q1 = *(const float4*)&pbuf[gb + 4];
      float4 q2 = *(const float4*)&pbuf[gb + 8];
      float4 q3 = *(const float4*)&pbuf[gb + 12];
      float c0  = q0.x + tcol[0],  c1  = q0.y + tcol[1],  c2  = q0.z + tcol[2],  c3  = q0.w + tcol[3];
      float c4  = q1.x + tcol[4],  c5  = q1.y + tcol[5],  c6  = q1.z + tcol[6],  c7  = q1.w + tcol[7];
      float c8  = q2.x + tcol[8],  c9  = q2.y + tcol[9],  c10 = q2.z + tcol[10], c11 = q2.w + tcol[11];
      float c12 = q3.x + tcol[12], c13 = q3.y + tcol[13], c14 = q3.z + tcol[14], c15 = q3.w + tcol[15];
      bool g; float v01,v23,v45,v67,v89,vAB,vCD,vEF,v03,v47,v8B,vCF,v07,v8F,best;
      int i01,i23,i45,i67,i89,iAB,iCD,iEF,i03,i47,i8B,iCF,i07,i8F,arg;
      g = c1  > c0;  v01 = g ? c1  : c0;  i01 = g ? 1  : 0;
      g = c3  > c2;  v23 = g ? c3  : c2;  i23 = g ? 3  : 2;
      g = c5  > c4;  v45 = g ? c5  : c4;  i45 = g ? 5  : 4;
      g = c7  > c6;  v67 = g ? c7  : c6;  i67 = g ? 7  : 6;
      g = c9  > c8;  v89 = g ? c9  : c8;  i89 = g ? 9  : 8;
      g = c11 > c10; vAB = g ? c11 : c10; iAB = g ? 11 : 10;
      g = c13 > c12; vCD = g ? c13 : c12; iCD = g ? 13 : 12;
      g = c15 > c14; vEF = g ? c15 : c14; iEF = g ? 15 : 14;
      g = v23 > v01; v03 = g ? v23 : v01; i03 = g ? i23 : i01;
      g = v67 > v45; v47 = g ? v67 : v45; i47 = g ? i67 : i45;
      g = vAB > v89; v8B = g ? vAB : v89; i8B = g ? iAB : i89;
      g = vEF > vCD; vCF = g ? vEF : vCD; iCF = g ? iEF : iCD;
      g = v47 > v03; v07 = g ? v47 : v03; i07 = g ? i47 : i03;
      g = vCF > v8B; v8F = g ? vCF : v8B; i8F = g ? iCF : i8B;
      g = v8F > v07; best = g ? v8F : v07; arg = g ? i8F : i07;
      v = best + ems[(l - l0) * Tn + tp];
      hl[(i * Sn + (l - l0)) * Tn + tp] = (uint8_t)arg;
    }
    qv[(((size_t)b * Cn + c) * Tn + i) * Tn + tp] = v;
    __syncthreads();
    const uint4* s4 = (const uint4*)hl;   // coalesced 16KB dump
    uint4* d4 = (uint4*)(hist + (size_t)bc * (Tn * Sn * Tn));
    for (int k = tid; k < (Tn * Sn * Tn) / 16; k += 256) d4[k] = s4[k];
  }
}

// ---------------- K_C: merged tail — folds read from LDS-staged q-blocks (r10 form) -
__global__ __launch_bounds__(512) void k_tail(
    const float* __restrict__ qv, const float* __restrict__ em,
    const float* __restrict__ start, const float* __restrict__ endt,
    const uint8_t* __restrict__ hist, const int* __restrict__ labels,
    const int* __restrict__ mask, const float* __restrict__ trans,
    const float* __restrict__ qmat, float* __restrict__ lossws,
    float* __restrict__ loss_out, float* __restrict__ tags) {
  int bid = blockIdx.x, tid = threadIdx.x;
  __shared__ float qs[Cn * Tn * Tn];     // 8 KB staged fold matrix
  if (bid >= Bn) {
    // ---- numerator + denominator fold -> llh contribution for b = bid-64 ----
    int b = bid - Bn;
    {
      float4 qv4 = *(((const float4*)qmat) + (size_t)b * 512 + tid);
      *(((float4*)qs) + tid) = qv4;
    }
    {
      int l = tid;                         // 512 threads = one l each
      int y = labels[b * Ln + l];
      int m = mask[b * Ln + l];
      float s;
      if (l == 0) s = start[y] + em[((size_t)b * Ln) * Tn + y];
      else s = m ? (trans[labels[b * Ln + l - 1] * Tn + y] + em[((size_t)b * Ln + l) * Tn + y]) : 0.f;
      int msum = m;
      for (int off = 32; off; off >>= 1) {
        s += __shfl_down(s, off);
        msum += __shfl_down(msum, off);
      }
      __shared__ float sw[8]; __shared__ int mw[8];
      __shared__ float snum;
      int wid = tid >> 6, ln = tid & 63;
      if (ln == 0) { sw[wid] = s; mw[wid] = msum; }
      __syncthreads();
      if (tid == 0) {
        float st = 0.f; int mt = 0;
        for (int wv = 0; wv < 8; ++wv) { st += sw[wv]; mt += mw[wv]; }
        snum = st + endt[labels[b * Ln + mt - 1]];
      }
      __syncthreads();                    // qs preload also complete by here
      if (tid < Tn) {                     // 16-lane log-space fold over LDS-staged qmat
        int k = tid;
        float p = start[k] + em[((size_t)b * Ln) * Tn + k];
        for (int c = 0; c < Cn; ++c) {
          float vals[Tn]; float mx = -3.0e38f;
#pragma unroll
          for (int i2 = 0; i2 < Tn; ++i2) {
            float cand = __shfl(p, i2, 16) + qs[c * 256 + i2 * 16 + k];
            vals[i2] = cand;
            mx = fmaxf(mx, cand);
          }
          float sm = 0.f;
#pragma unroll
          for (int i2 = 0; i2 < Tn; ++i2) sm += __expf(vals[i2] - mx);
          p = mx + __logf(sm);
        }
        float x = p + endt[k];
        float mx = x;
        mx = fmaxf(mx, __shfl_xor(mx, 1));
        mx = fmaxf(mx, __shfl_xor(mx, 2));
        mx = fmaxf(mx, __shfl_xor(mx, 4));
        mx = fmaxf(mx, __shfl_xor(mx, 8));
        float e = __expf(x - mx);
        e += __shfl_xor(e, 1);
        e += __shfl_xor(e, 2);
        e += __shfl_xor(e, 4);
        e += __shfl_xor(e, 8);
        float denom = mx + __logf(e);
        if (k == 0) {
          atomicAdd(&lossws[0], snum - denom);
          __threadfence();
          int ticket = atomicAdd((int*)lossws + 1, 1);
          if (ticket == Bn - 1) {         // last numer block finalizes loss
            __threadfence();
            float total = atomicAdd(&lossws[0], 0.f);
            loss_out[0] = -total * (1.0f / Bn);
          }
        }
      }
    }
    return;
  }
  // ---- Viterbi fold + parallel backtrack for b = bid ----
  int b = bid;
  __shared__ int Bs[Cn][Tn];
  __shared__ int bnd[Cn + 1];
  {
    float4 qv4 = *(((const float4*)qv) + (size_t)b * 512 + tid);  // stage qv block
    *(((float4*)qs) + tid) = qv4;
  }
  __syncthreads();
  if (tid < Tn) {
    int k = tid;
    float p = start[k] + em[((size_t)b * Ln) * Tn + k];
    for (int c = 0; c < Cn; ++c) {
      float best = -3.0e38f; int arg = 0;
#pragma unroll
      for (int i2 = 0; i2 < Tn; ++i2) {
        float cand = __shfl(p, i2, 16) + qs[c * 256 + i2 * 16 + k];
        bool g = cand > best;
        arg = g ? i2 : arg;
        best = g ? cand : best;
      }
      Bs[c][k] = arg;
      p = best;
    }
    float x = p + endt[k]; int idx = k;   // first-max argmax over k
#pragma unroll
    for (int d = 1; d < 16; d <<= 1) {
      float xo = __shfl_xor(x, d);
      int io = __shfl_xor(idx, d);
      bool take = (xo > x) || (xo == x && io < idx);
      x = take ? xo : x;
      idx = take ? io : idx;
    }
    if (k == 0) bnd[Cn] = idx;
  }
  __syncthreads();
  if (tid == 0) {
    int t = bnd[Cn];
    for (int c = Cn - 1; c >= 0; --c) { t = Bs[c][t]; bnd[c] = t; }
  }
  __syncthreads();
  int w = tid >> 6, lane = tid & 63;      // wave w backtracks chunk w
  int istar = bnd[w];
  int cur = bnd[w + 1];
  int l0 = w * Sn;
  const uint4* hp = (const uint4*)(hist + ((size_t)(b * Cn + w) * Tn + istar) * (Sn * Tn));
  uint4 hh = hp[lane];
  float mytag = (lane == 63) ? (float)cur : 0.f;
  for (int l = l0 + 63; l >= l0 + 1; --l) {
    int sl = l - l0;
    unsigned w0 = __shfl((int)hh.x, sl);
    unsigned w1 = __shfl((int)hh.y, sl);
    unsigned w2 = __shfl((int)hh.z, sl);
    unsigned w3 = __shfl((int)hh.w, sl);
    unsigned word = (cur < 8) ? ((cur < 4) ? w0 : w1) : ((cur < 12) ? w2 : w3);
    cur = (int)((word >> ((cur & 3) * 8)) & 0xff);
    if (lane == sl - 1) mytag = (float)cur;
  }
  tags[(size_t)b * Ln + l0 + lane] = mytag;
}

extern "C" void kernel_launch(void* const* d_in, const int* in_sizes, int n_in,
                              void* d_out, int out_size, void* d_ws, size_t ws_size,
                              hipStream_t stream) {
  const float* hs     = (const float*)d_in[0];
  const int*   mask   = (const int*)d_in[1];
  const int*   labels = (const int*)d_in[2];
  const float* W      = (const float*)d_in[3];
  const float* bias   = (const float*)d_in[4];
  const float* start  = (const float*)d_in[5];
  const float* endt   = (const float*)d_in[6];
  const float* trans  = (const float*)d_in[7];
  float* out = (float*)d_out;

  // Workspace (~19.9 MB, NO aliasing — partial & hist are concurrently live in K_B):
  //   em      @ 0          : 2,097,152
  //   qmat    @ 2,097,152  :   524,288
  //   qv      @ 2,621,440  :   524,288
  //   lossws  @ 3,145,728  :     4,096  (accum float + ticket int)
  //   partial @ 3,149,824  : 8,388,608  (4*32768*16*4)
  //   hist    @ 11,538,432 : 8,388,608
  char* ws = (char*)d_ws;
  float*   em      = (float*)(ws);
  float*   qmat    = (float*)(ws + 2097152);
  float*   qv      = (float*)(ws + 2621440);
  float*   lossws  = (float*)(ws + 3145728);
  float*   partial = (float*)(ws + 3149824);
  uint8_t* hist    = (uint8_t*)(ws + 11538432);

  hipLaunchKernelGGL(k_gemm_part, dim3(1024), dim3(256), 0, stream, hs, W, partial, lossws);
  hipLaunchKernelGGL(k_em_scan,   dim3(1024), dim3(256), 0, stream, partial, bias, mask, trans, em, qmat, qv, hist);
  hipLaunchKernelGGL(k_tail,      dim3(128),  dim3(512), 0, stream, qv, em, start, endt, hist, labels, mask, trans, qmat, lossws, out, out + 1);
}